// Round 5
// baseline (388.757 us; speedup 1.0000x reference)
//
#include <hip/hip_runtime.h>
#include <cstddef>
#include <cstdint>

// ---------------------------------------------------------------------------
// MAB fused block. B=4 N=M=2048 C=1024 H=16 d=64. bf16 MFMA internally.
// R5: all-bf16 (fp8 path reverted — R4 NaN). Attention reaches 3 blocks/CU by
// aliasing K-tile and V-tile in one 16 KB LDS buffer (49 KB total), at the
// cost of one extra barrier per kt. GEMMs: BK=64, 3 blocks/CU.
// ---------------------------------------------------------------------------

typedef unsigned short ushort_t;
typedef __attribute__((ext_vector_type(8))) short bf16x8;
typedef __attribute__((ext_vector_type(4))) float floatx4;
typedef __attribute__((ext_vector_type(8))) unsigned short us8;
typedef __attribute__((ext_vector_type(4))) unsigned short us4;

__device__ __forceinline__ ushort_t f2bf(float x) {   // RNE
  union { float f; unsigned u; } v; v.f = x;
  unsigned r = v.u + 0x7FFFu + ((v.u >> 16) & 1u);
  return (ushort_t)(r >> 16);
}
__device__ __forceinline__ float bf2f(ushort_t x) {
  union { unsigned u; float f; } v; v.u = ((unsigned)x) << 16;
  return v.f;
}
// pack two f32 -> [bf16(b):bf16(a)] via +0x8000 + v_perm (round-half-up)
__device__ __forceinline__ unsigned pk2(float a, float b) {
  union { float f; unsigned u; } x, y; x.f = a; y.f = b;
  return __builtin_amdgcn_perm(y.u + 0x8000u, x.u + 0x8000u, 0x07060302u);
}
__device__ __forceinline__ floatx4 mfma16(bf16x8 a, bf16x8 b, floatx4 c) {
  return __builtin_amdgcn_mfma_f32_16x16x32_bf16(a, b, c, 0, 0, 0);
}
__device__ __forceinline__ void gld_lds16(const void* g, void* l) {
  __builtin_amdgcn_global_load_lds(
      (const __attribute__((address_space(1))) unsigned int*)g,
      (__attribute__((address_space(3))) unsigned int*)l, 16, 0, 0);
}

// ---------------------------------------------------------------------------
// f32 -> bf16, 8 elems/thread, 4 tensors by blockIdx.z.
// ---------------------------------------------------------------------------
__global__ void cvt4(const float* __restrict__ i0, const float* __restrict__ i1,
                     const float* __restrict__ i2, const float* __restrict__ i3,
                     ushort_t* __restrict__ o0, ushort_t* __restrict__ o1,
                     ushort_t* __restrict__ o2, ushort_t* __restrict__ o3, int n8) {
  int z = blockIdx.z;
  const float* in = z == 0 ? i0 : z == 1 ? i1 : z == 2 ? i2 : i3;
  ushort_t* out = z == 0 ? o0 : z == 1 ? o1 : z == 2 ? o2 : o3;
  int i = blockIdx.x * 256 + threadIdx.x;
  if (i < n8) {
    const float4* p = (const float4*)in + (size_t)i * 2;
    float4 a = p[0], b = p[1];
    uint4 o;
    o.x = pk2(a.x, a.y); o.y = pk2(a.z, a.w);
    o.z = pk2(b.x, b.y); o.w = pk2(b.z, b.w);
    *((uint4*)out + i) = o;
  }
}

// ---------------------------------------------------------------------------
// Fused QKV projections. z=0: Qp; z=1: Kp; z=2: Vt (bf16, transposed
// [1024 dv][8192 kv]). 128x128 tile, BK=64, 3-bit XOR chunk swizzle
// (same form as R3's proven attention Ks staging).
// ---------------------------------------------------------------------------
__global__ __launch_bounds__(256, 3)
void gemm_qkv(const ushort_t* __restrict__ Qb, const ushort_t* __restrict__ Kb,
              const ushort_t* __restrict__ Wqb, const ushort_t* __restrict__ Wkb,
              const ushort_t* __restrict__ Wvb,
              const float* __restrict__ bq, const float* __restrict__ bk,
              const float* __restrict__ bv,
              ushort_t* __restrict__ Qp, ushort_t* __restrict__ Kp,
              ushort_t* __restrict__ Vt)
{
  const int Kd = 1024, Nn = 1024;
  const int z = blockIdx.z;
  const ushort_t* Ab = (z == 0) ? Qb : Kb;
  const ushort_t* Bw = (z == 0) ? Wqb : (z == 1) ? Wkb : Wvb;
  const float* bias  = (z == 0) ? bq : (z == 1) ? bk : bv;

  __shared__ __align__(16) ushort_t As[128][64];
  __shared__ __align__(16) ushort_t Bs[128][64];
  const int tid = threadIdx.x;
  const int lane = tid & 63, wave = tid >> 6;
  const int wm = (wave >> 1) * 64, wn = (wave & 1) * 64;
  const int rq = lane & 15, kg = lane >> 4;
  const int row0 = blockIdx.y * 128, col0 = blockIdx.x * 128;

  const int st_sub = lane >> 3;                 // row within 8-row group
  const int st_cs  = (lane & 7) ^ st_sub;       // swizzled source 16B chunk

  floatx4 acc[4][4];
#pragma unroll
  for (int i = 0; i < 4; ++i)
#pragma unroll
    for (int j = 0; j < 4; ++j) acc[i][j] = (floatx4){0.f, 0.f, 0.f, 0.f};

  for (int k0 = 0; k0 < Kd; k0 += 64) {
    __syncthreads();
#pragma unroll
    for (int r = 0; r < 4; ++r) {
      int i = wave * 4 + r;                     // 0..15, 8 rows each
      int row = i * 8 + st_sub;
      gld_lds16(Ab + (size_t)(row0 + row) * Kd + k0 + st_cs * 8, (ushort_t*)As + i * 512);
      gld_lds16(Bw + (size_t)(col0 + row) * Kd + k0 + st_cs * 8, (ushort_t*)Bs + i * 512);
    }
    __syncthreads();
#pragma unroll
    for (int kq = 0; kq < 2; ++kq) {
      bf16x8 af[4], bfr[4];
#pragma unroll
      for (int mi = 0; mi < 4; ++mi)
        af[mi] = *(const bf16x8*)&As[wm + mi*16 + rq][((kq*4 + kg) ^ (rq & 7)) * 8];
#pragma unroll
      for (int ni = 0; ni < 4; ++ni)
        bfr[ni] = *(const bf16x8*)&Bs[wn + ni*16 + rq][((kq*4 + kg) ^ (rq & 7)) * 8];
#pragma unroll
      for (int mi = 0; mi < 4; ++mi)
#pragma unroll
        for (int ni = 0; ni < 4; ++ni)
          acc[mi][ni] = mfma16(af[mi], bfr[ni], acc[mi][ni]);
    }
  }

  float bv4[4];
#pragma unroll
  for (int ni = 0; ni < 4; ++ni) bv4[ni] = bias[col0 + wn + ni*16 + rq];

  if (z < 2) {
    ushort_t* Cb = (z == 0) ? Qp : Kp;
#pragma unroll
    for (int mi = 0; mi < 4; ++mi)
#pragma unroll
      for (int ni = 0; ni < 4; ++ni)
#pragma unroll
        for (int rr = 0; rr < 4; ++rr) {
          int row = row0 + wm + mi*16 + kg*4 + rr;
          int col = col0 + wn + ni*16 + rq;
          Cb[(size_t)row * Nn + col] = f2bf(acc[mi][ni][rr] + bv4[ni]);
        }
  } else {
#pragma unroll
    for (int mi = 0; mi < 4; ++mi)
#pragma unroll
      for (int ni = 0; ni < 4; ++ni) {
        int col = col0 + wn + ni*16 + rq;       // dv
        int r0  = row0 + wm + mi*16 + kg*4;     // kv (mult of 4)
        us4 o = { f2bf(acc[mi][ni][0] + bv4[ni]), f2bf(acc[mi][ni][1] + bv4[ni]),
                  f2bf(acc[mi][ni][2] + bv4[ni]), f2bf(acc[mi][ni][3] + bv4[ni]) };
        *(us4*)(Vt + (size_t)col * 8192 + r0) = o;
      }
  }
}

// ---------------------------------------------------------------------------
// Output GEMM: out = bf2f(Ob) + relu(Ob*Wo^T + bo), f32 out. BK=64.
// ---------------------------------------------------------------------------
__global__ __launch_bounds__(256, 3)
void gemm_out(const ushort_t* __restrict__ Ob, const ushort_t* __restrict__ Bw,
              const float* __restrict__ bias, float* __restrict__ Out)
{
  const int Kd = 1024, Nn = 1024;
  __shared__ __align__(16) ushort_t As[128][64];
  __shared__ __align__(16) ushort_t Bs[128][64];
  const int tid = threadIdx.x;
  const int lane = tid & 63, wave = tid >> 6;
  const int wm = (wave >> 1) * 64, wn = (wave & 1) * 64;
  const int rq = lane & 15, kg = lane >> 4;
  const int row0 = blockIdx.y * 128, col0 = blockIdx.x * 128;

  const int st_sub = lane >> 3;
  const int st_cs  = (lane & 7) ^ st_sub;

  floatx4 acc[4][4];
#pragma unroll
  for (int i = 0; i < 4; ++i)
#pragma unroll
    for (int j = 0; j < 4; ++j) acc[i][j] = (floatx4){0.f, 0.f, 0.f, 0.f};

  for (int k0 = 0; k0 < Kd; k0 += 64) {
    __syncthreads();
#pragma unroll
    for (int r = 0; r < 4; ++r) {
      int i = wave * 4 + r;
      int row = i * 8 + st_sub;
      gld_lds16(Ob + (size_t)(row0 + row) * Kd + k0 + st_cs * 8, (ushort_t*)As + i * 512);
      gld_lds16(Bw + (size_t)(col0 + row) * Kd + k0 + st_cs * 8, (ushort_t*)Bs + i * 512);
    }
    __syncthreads();
#pragma unroll
    for (int kq = 0; kq < 2; ++kq) {
      bf16x8 af[4], bfr[4];
#pragma unroll
      for (int mi = 0; mi < 4; ++mi)
        af[mi] = *(const bf16x8*)&As[wm + mi*16 + rq][((kq*4 + kg) ^ (rq & 7)) * 8];
#pragma unroll
      for (int ni = 0; ni < 4; ++ni)
        bfr[ni] = *(const bf16x8*)&Bs[wn + ni*16 + rq][((kq*4 + kg) ^ (rq & 7)) * 8];
#pragma unroll
      for (int mi = 0; mi < 4; ++mi)
#pragma unroll
        for (int ni = 0; ni < 4; ++ni)
          acc[mi][ni] = mfma16(af[mi], bfr[ni], acc[mi][ni]);
    }
  }

  float bv4[4];
#pragma unroll
  for (int ni = 0; ni < 4; ++ni) bv4[ni] = bias[col0 + wn + ni*16 + rq];
#pragma unroll
  for (int mi = 0; mi < 4; ++mi)
#pragma unroll
    for (int ni = 0; ni < 4; ++ni)
#pragma unroll
      for (int rr = 0; rr < 4; ++rr) {
        int row = row0 + wm + mi*16 + kg*4 + rr;
        int col = col0 + wn + ni*16 + rq;
        size_t idx = (size_t)row * Nn + col;
        float pre = acc[mi][ni][rr] + bv4[ni];
        Out[idx] = bf2f(Ob[idx]) + (pre > 0.f ? pre : 0.f);
      }
}

// ---------------------------------------------------------------------------
// Flash attention (no-max softmax). BQ=128, BKV=128, d=64, all bf16.
// S^T = K*Q^T. K-tile [128][64] and V^T-tile [64][128] ALIAS one 16 KB LDS
// buffer (K read only in S phase, V only in PV; separated by barriers).
// Ps[128][128] bf16 with 4-bit XOR swizzle (R3-proven). 49 KB -> 3 blk/CU.
// Per kt: sync | stage K | sync | S, exp, l | sync | stage V + write P |
// sync | PV.
// ---------------------------------------------------------------------------
__global__ __launch_bounds__(256, 3)
void attn_kernel(const ushort_t* __restrict__ Qp,
                 const ushort_t* __restrict__ Kp,
                 const ushort_t* __restrict__ Vt,
                 ushort_t* __restrict__ Ob)
{
  const float sc2 = 0.045084439f;  // (1/32) * log2(e)
  const int qt = blockIdx.x;       // 0..15
  const int bh = blockIdx.y;       // 0..63
  const int b = bh >> 4, h = bh & 15;
  const int q0 = qt * 128;

  __shared__ __align__(16) ushort_t KVs[8192];     // K[128][64] / V^T[64][128]
  __shared__ __align__(16) ushort_t Ps[128][128];
  __shared__ float reds[2][128];

  const int tid = threadIdx.x, lane = tid & 63, wave = tid >> 6;
  const int whalf = wave >> 1;
  const int wsec  = wave & 1;
  const int rq = lane & 15, kg = lane >> 4;

  const size_t qkbase = (size_t)(b * 2048) * 1024 + h * 64;

  // stage Q tile (128x64) into KVs, 3-bit chunk swizzle
#pragma unroll
  for (int r = 0; r < 4; ++r) {
    int i = wave * 4 + r;
    int row = i * 8 + (lane >> 3);
    int cs = (lane & 7) ^ (lane >> 3);
    gld_lds16(Qp + qkbase + (size_t)(q0 + row) * 1024 + cs * 8, KVs + i * 512);
  }
  __syncthreads();

  // preload Q B-frags scaled by sc2: aq[ni][kq], q = wsec*64+ni*16+rq
  bf16x8 aq[4][2];
#pragma unroll
  for (int ni = 0; ni < 4; ++ni)
#pragma unroll
    for (int kq = 0; kq < 2; ++kq) {
      int row = wsec*64 + ni*16 + rq;
      int ch = (kq*4 + kg) ^ (rq & 7);
      bf16x8 t = *(const bf16x8*)&KVs[row * 64 + ch * 8];
#pragma unroll
      for (int e = 0; e < 8; ++e)
        t[e] = (short)f2bf(bf2f((ushort_t)t[e]) * sc2);
      aq[ni][kq] = t;
    }

  floatx4 oacc[4][2];
  float l_st[4];
#pragma unroll
  for (int mi = 0; mi < 4; ++mi) {
    oacc[mi][0] = (floatx4){0.f,0.f,0.f,0.f};
    oacc[mi][1] = (floatx4){0.f,0.f,0.f,0.f};
  }
#pragma unroll
  for (int ni = 0; ni < 4; ++ni) l_st[ni] = 0.f;

  for (int kt = 0; kt < 16; ++kt) {
    const int kv0 = kt * 128;
    __syncthreads();   // (1) prev PV done reading Ps + KVs(V); aq preload done
    // stage K (128 kv x 64 d) into KVs
#pragma unroll
    for (int r = 0; r < 4; ++r) {
      int i = wave * 4 + r;
      int row = i * 8 + (lane >> 3);
      int cs = (lane & 7) ^ (lane >> 3);
      gld_lds16(Kp + qkbase + (size_t)(kv0 + row) * 1024 + cs * 8, KVs + i * 512);
    }
    __syncthreads();   // (2) K landed

    // S^T = K * Q^T  (mi = kv tile, ni = q tile)
    floatx4 s[4][4];
#pragma unroll
    for (int mi = 0; mi < 4; ++mi)
#pragma unroll
      for (int ni = 0; ni < 4; ++ni) s[mi][ni] = (floatx4){0.f,0.f,0.f,0.f};
#pragma unroll
    for (int kq = 0; kq < 2; ++kq) {
      bf16x8 ak[4];
#pragma unroll
      for (int mi = 0; mi < 4; ++mi) {
        int row = whalf*64 + mi*16 + rq;
        int ch = (kq*4 + kg) ^ (rq & 7);
        ak[mi] = *(const bf16x8*)&KVs[row * 64 + ch * 8];
      }
#pragma unroll
      for (int mi = 0; mi < 4; ++mi)
#pragma unroll
        for (int ni = 0; ni < 4; ++ni)
          s[mi][ni] = mfma16(ak[mi], aq[ni][kq], s[mi][ni]);
    }
    __syncthreads();   // (3) all waves done reading K from KVs

    // stage V^T (64 dv x 128 kv) into KVs (aliased over K)
#pragma unroll
    for (int r = 0; r < 4; ++r) {
      int i = wave * 4 + r;
      int dv = i * 4 + (lane >> 4);
      int cs = (lane & 15) ^ (dv & 7);
      gld_lds16(Vt + (size_t)(h*64 + dv) * 8192 + b * 2048 + kv0 + cs * 8,
                KVs + i * 512);
    }

    // p = 2^s ; per-lane partial row sums; pack + write Ps
#pragma unroll
    for (int mi = 0; mi < 4; ++mi)
#pragma unroll
      for (int ni = 0; ni < 4; ++ni)
#pragma unroll
        for (int rr = 0; rr < 4; ++rr)
          s[mi][ni][rr] = __builtin_amdgcn_exp2f(s[mi][ni][rr]);
#pragma unroll
    for (int ni = 0; ni < 4; ++ni) {
      float t = 0.f;
#pragma unroll
      for (int mi = 0; mi < 4; ++mi)
        t += (s[mi][ni][0] + s[mi][ni][1]) + (s[mi][ni][2] + s[mi][ni][3]);
      l_st[ni] += t;
    }
#pragma unroll
    for (int mi = 0; mi < 4; ++mi)
#pragma unroll
      for (int ni = 0; ni < 4; ++ni) {
        int q = wsec*64 + ni*16 + rq;
        int chunk = (whalf*8 + mi*2 + (kg >> 1)) ^ rq;   // kv>>3 swizzled by q&15
        int colu = chunk*8 + (kg & 1)*4;
        uint2 w;
        w.x = pk2(s[mi][ni][0], s[mi][ni][1]);
        w.y = pk2(s[mi][ni][2], s[mi][ni][3]);
        *(uint2*)&Ps[q][colu] = w;
      }
    __syncthreads();   // (4) V + Ps landed

    // O += P V : wave = (whalf: 64 q rows) x (wsec: 32 dv cols)
#pragma unroll
    for (int kp = 0; kp < 4; ++kp) {
      bf16x8 pf[4], vf[2];
#pragma unroll
      for (int mi = 0; mi < 4; ++mi) {
        int row = whalf*64 + mi*16 + rq;
        int slot = (kp*4 + kg) ^ rq;    // unswizzle by q&15
        pf[mi] = *(const bf16x8*)&Ps[row][slot * 8];
      }
#pragma unroll
      for (int n2 = 0; n2 < 2; ++n2) {
        int dv = wsec*32 + n2*16 + rq;
        int ch = (kp*4 + kg) ^ (rq & 7);
        vf[n2] = *(const bf16x8*)&KVs[dv * 128 + ch * 8];
      }
#pragma unroll
      for (int mi = 0; mi < 4; ++mi)
#pragma unroll
        for (int n2 = 0; n2 < 2; ++n2)
          oacc[mi][n2] = mfma16(pf[mi], vf[n2], oacc[mi][n2]);
    }
  }

  // combine l: across kg groups, then across kv-half waves via LDS
#pragma unroll
  for (int ni = 0; ni < 4; ++ni) {
    l_st[ni] += __shfl_xor(l_st[ni], 16, 64);
    l_st[ni] += __shfl_xor(l_st[ni], 32, 64);
  }
  if (lane < 16) {
#pragma unroll
    for (int ni = 0; ni < 4; ++ni)
      reds[whalf][wsec*64 + ni*16 + rq] = l_st[ni];
  }
  __syncthreads();

  // epilogue: Oh = Qh + O/l
#pragma unroll
  for (int mi = 0; mi < 4; ++mi)
#pragma unroll
    for (int rr = 0; rr < 4; ++rr) {
      int row = whalf*64 + mi*16 + kg*4 + rr;
      float linv = 1.0f / (reds[0][row] + reds[1][row]);
#pragma unroll
      for (int n2 = 0; n2 < 2; ++n2) {
        int col = wsec*32 + n2*16 + rq;
        size_t idx = qkbase + (size_t)(q0 + row) * 1024 + col;
        float ov = oacc[mi][n2][rr] * linv + bf2f(Qp[idx]);
        Ob[idx] = f2bf(ov);
      }
    }
}

// ---------------------------------------------------------------------------
extern "C" void kernel_launch(void* const* d_in, const int* in_sizes, int n_in,
                              void* d_out, int out_size, void* d_ws, size_t ws_size,
                              hipStream_t stream)
{
  const float* Q  = (const float*)d_in[0];
  const float* K  = (const float*)d_in[1];
  const float* Wq = (const float*)d_in[2];
  const float* bq = (const float*)d_in[3];
  const float* Wk = (const float*)d_in[4];
  const float* bk = (const float*)d_in[5];
  const float* Wv = (const float*)d_in[6];
  const float* bv = (const float*)d_in[7];
  const float* Wo = (const float*)d_in[8];
  const float* bo = (const float*)d_in[9];
  float* Out = (float*)d_out;

  ushort_t* ws = (ushort_t*)d_ws;
  const size_t E = (size_t)8192 * 1024;
  const size_t WSZ = (size_t)1024 * 1024;
  ushort_t* Qb  = ws;            // aliased by Ob after attention
  ushort_t* Kb  = ws + E;
  ushort_t* Qp  = ws + 2*E;
  ushort_t* Kp  = ws + 3*E;
  ushort_t* Vt  = ws + 4*E;      // bf16 V^T [1024][8192]
  ushort_t* Wqb = ws + 5*E;
  ushort_t* Wkb = ws + 5*E + WSZ;
  ushort_t* Wvb = ws + 5*E + 2*WSZ;
  ushort_t* Wob = ws + 5*E + 3*WSZ;
  ushort_t* Ob  = Qb;

  cvt4<<<dim3(4096, 1, 2), 256, 0, stream>>>(Q, K, K, K, Qb, Kb, Kb, Kb, 1048576);
  cvt4<<<dim3(512, 1, 4), 256, 0, stream>>>(Wq, Wk, Wv, Wo, Wqb, Wkb, Wvb, Wob, 131072);

  dim3 blk(256);
  gemm_qkv<<<dim3(8, 64, 3), blk, 0, stream>>>(Qb, Kb, Wqb, Wkb, Wvb,
                                               bq, bk, bv, Qp, Kp, Vt);
  attn_kernel<<<dim3(16, 64), blk, 0, stream>>>(Qp, Kp, Vt, Ob);
  gemm_out<<<dim3(8, 64), blk, 0, stream>>>(Ob, Wob, bo, Out);
}

// Round 6
// 322.468 us; speedup vs baseline: 1.2056x; 1.2056x over previous
//
#include <hip/hip_runtime.h>
#include <cstddef>
#include <cstdint>

// ---------------------------------------------------------------------------
// MAB fused block. B=4 N=M=2048 C=1024 H=16 d=64. bf16 MFMA internally.
// R6: R5 structure with launch_bounds reverted to (256,2) everywhere.
// R5 lesson: the 2nd launch_bounds arg is a register-allocator FLOOR, not an
// occupancy lever — (256,3) forced VGPR 124->84 and spilled ~430 MB scratch.
// Occupancy comes from resources: attn LDS 49 KB (K/V aliased) + ~124 VGPR
// -> 3 blocks/CU naturally; BK=64 GEMMs at 32 KB LDS -> up to 4 blocks/CU.
// ---------------------------------------------------------------------------

typedef unsigned short ushort_t;
typedef __attribute__((ext_vector_type(8))) short bf16x8;
typedef __attribute__((ext_vector_type(4))) float floatx4;
typedef __attribute__((ext_vector_type(8))) unsigned short us8;
typedef __attribute__((ext_vector_type(4))) unsigned short us4;

__device__ __forceinline__ ushort_t f2bf(float x) {   // RNE
  union { float f; unsigned u; } v; v.f = x;
  unsigned r = v.u + 0x7FFFu + ((v.u >> 16) & 1u);
  return (ushort_t)(r >> 16);
}
__device__ __forceinline__ float bf2f(ushort_t x) {
  union { unsigned u; float f; } v; v.u = ((unsigned)x) << 16;
  return v.f;
}
// pack two f32 -> [bf16(b):bf16(a)] via +0x8000 + v_perm (round-half-up)
__device__ __forceinline__ unsigned pk2(float a, float b) {
  union { float f; unsigned u; } x, y; x.f = a; y.f = b;
  return __builtin_amdgcn_perm(y.u + 0x8000u, x.u + 0x8000u, 0x07060302u);
}
__device__ __forceinline__ floatx4 mfma16(bf16x8 a, bf16x8 b, floatx4 c) {
  return __builtin_amdgcn_mfma_f32_16x16x32_bf16(a, b, c, 0, 0, 0);
}
__device__ __forceinline__ void gld_lds16(const void* g, void* l) {
  __builtin_amdgcn_global_load_lds(
      (const __attribute__((address_space(1))) unsigned int*)g,
      (__attribute__((address_space(3))) unsigned int*)l, 16, 0, 0);
}

// ---------------------------------------------------------------------------
// f32 -> bf16, 8 elems/thread, 4 tensors by blockIdx.z.
// ---------------------------------------------------------------------------
__global__ void cvt4(const float* __restrict__ i0, const float* __restrict__ i1,
                     const float* __restrict__ i2, const float* __restrict__ i3,
                     ushort_t* __restrict__ o0, ushort_t* __restrict__ o1,
                     ushort_t* __restrict__ o2, ushort_t* __restrict__ o3, int n8) {
  int z = blockIdx.z;
  const float* in = z == 0 ? i0 : z == 1 ? i1 : z == 2 ? i2 : i3;
  ushort_t* out = z == 0 ? o0 : z == 1 ? o1 : z == 2 ? o2 : o3;
  int i = blockIdx.x * 256 + threadIdx.x;
  if (i < n8) {
    const float4* p = (const float4*)in + (size_t)i * 2;
    float4 a = p[0], b = p[1];
    uint4 o;
    o.x = pk2(a.x, a.y); o.y = pk2(a.z, a.w);
    o.z = pk2(b.x, b.y); o.w = pk2(b.z, b.w);
    *((uint4*)out + i) = o;
  }
}

// ---------------------------------------------------------------------------
// Fused QKV projections. z=0: Qp; z=1: Kp; z=2: Vt (bf16, transposed
// [1024 dv][8192 kv]). 128x128 tile, BK=64, 3-bit XOR chunk swizzle.
// ---------------------------------------------------------------------------
__global__ __launch_bounds__(256, 2)
void gemm_qkv(const ushort_t* __restrict__ Qb, const ushort_t* __restrict__ Kb,
              const ushort_t* __restrict__ Wqb, const ushort_t* __restrict__ Wkb,
              const ushort_t* __restrict__ Wvb,
              const float* __restrict__ bq, const float* __restrict__ bk,
              const float* __restrict__ bv,
              ushort_t* __restrict__ Qp, ushort_t* __restrict__ Kp,
              ushort_t* __restrict__ Vt)
{
  const int Kd = 1024, Nn = 1024;
  const int z = blockIdx.z;
  const ushort_t* Ab = (z == 0) ? Qb : Kb;
  const ushort_t* Bw = (z == 0) ? Wqb : (z == 1) ? Wkb : Wvb;
  const float* bias  = (z == 0) ? bq : (z == 1) ? bk : bv;

  __shared__ __align__(16) ushort_t As[128][64];
  __shared__ __align__(16) ushort_t Bs[128][64];
  const int tid = threadIdx.x;
  const int lane = tid & 63, wave = tid >> 6;
  const int wm = (wave >> 1) * 64, wn = (wave & 1) * 64;
  const int rq = lane & 15, kg = lane >> 4;
  const int row0 = blockIdx.y * 128, col0 = blockIdx.x * 128;

  const int st_sub = lane >> 3;                 // row within 8-row group
  const int st_cs  = (lane & 7) ^ st_sub;       // swizzled source 16B chunk

  floatx4 acc[4][4];
#pragma unroll
  for (int i = 0; i < 4; ++i)
#pragma unroll
    for (int j = 0; j < 4; ++j) acc[i][j] = (floatx4){0.f, 0.f, 0.f, 0.f};

  for (int k0 = 0; k0 < Kd; k0 += 64) {
    __syncthreads();
#pragma unroll
    for (int r = 0; r < 4; ++r) {
      int i = wave * 4 + r;                     // 0..15, 8 rows each
      int row = i * 8 + st_sub;
      gld_lds16(Ab + (size_t)(row0 + row) * Kd + k0 + st_cs * 8, (ushort_t*)As + i * 512);
      gld_lds16(Bw + (size_t)(col0 + row) * Kd + k0 + st_cs * 8, (ushort_t*)Bs + i * 512);
    }
    __syncthreads();
#pragma unroll
    for (int kq = 0; kq < 2; ++kq) {
      bf16x8 af[4], bfr[4];
#pragma unroll
      for (int mi = 0; mi < 4; ++mi)
        af[mi] = *(const bf16x8*)&As[wm + mi*16 + rq][((kq*4 + kg) ^ (rq & 7)) * 8];
#pragma unroll
      for (int ni = 0; ni < 4; ++ni)
        bfr[ni] = *(const bf16x8*)&Bs[wn + ni*16 + rq][((kq*4 + kg) ^ (rq & 7)) * 8];
#pragma unroll
      for (int mi = 0; mi < 4; ++mi)
#pragma unroll
        for (int ni = 0; ni < 4; ++ni)
          acc[mi][ni] = mfma16(af[mi], bfr[ni], acc[mi][ni]);
    }
  }

  float bv4[4];
#pragma unroll
  for (int ni = 0; ni < 4; ++ni) bv4[ni] = bias[col0 + wn + ni*16 + rq];

  if (z < 2) {
    ushort_t* Cb = (z == 0) ? Qp : Kp;
#pragma unroll
    for (int mi = 0; mi < 4; ++mi)
#pragma unroll
      for (int ni = 0; ni < 4; ++ni)
#pragma unroll
        for (int rr = 0; rr < 4; ++rr) {
          int row = row0 + wm + mi*16 + kg*4 + rr;
          int col = col0 + wn + ni*16 + rq;
          Cb[(size_t)row * Nn + col] = f2bf(acc[mi][ni][rr] + bv4[ni]);
        }
  } else {
#pragma unroll
    for (int mi = 0; mi < 4; ++mi)
#pragma unroll
      for (int ni = 0; ni < 4; ++ni) {
        int col = col0 + wn + ni*16 + rq;       // dv
        int r0  = row0 + wm + mi*16 + kg*4;     // kv (mult of 4)
        us4 o = { f2bf(acc[mi][ni][0] + bv4[ni]), f2bf(acc[mi][ni][1] + bv4[ni]),
                  f2bf(acc[mi][ni][2] + bv4[ni]), f2bf(acc[mi][ni][3] + bv4[ni]) };
        *(us4*)(Vt + (size_t)col * 8192 + r0) = o;
      }
  }
}

// ---------------------------------------------------------------------------
// Output GEMM: out = bf2f(Ob) + relu(Ob*Wo^T + bo), f32 out. BK=64.
// ---------------------------------------------------------------------------
__global__ __launch_bounds__(256, 2)
void gemm_out(const ushort_t* __restrict__ Ob, const ushort_t* __restrict__ Bw,
              const float* __restrict__ bias, float* __restrict__ Out)
{
  const int Kd = 1024, Nn = 1024;
  __shared__ __align__(16) ushort_t As[128][64];
  __shared__ __align__(16) ushort_t Bs[128][64];
  const int tid = threadIdx.x;
  const int lane = tid & 63, wave = tid >> 6;
  const int wm = (wave >> 1) * 64, wn = (wave & 1) * 64;
  const int rq = lane & 15, kg = lane >> 4;
  const int row0 = blockIdx.y * 128, col0 = blockIdx.x * 128;

  const int st_sub = lane >> 3;
  const int st_cs  = (lane & 7) ^ st_sub;

  floatx4 acc[4][4];
#pragma unroll
  for (int i = 0; i < 4; ++i)
#pragma unroll
    for (int j = 0; j < 4; ++j) acc[i][j] = (floatx4){0.f, 0.f, 0.f, 0.f};

  for (int k0 = 0; k0 < Kd; k0 += 64) {
    __syncthreads();
#pragma unroll
    for (int r = 0; r < 4; ++r) {
      int i = wave * 4 + r;
      int row = i * 8 + st_sub;
      gld_lds16(Ob + (size_t)(row0 + row) * Kd + k0 + st_cs * 8, (ushort_t*)As + i * 512);
      gld_lds16(Bw + (size_t)(col0 + row) * Kd + k0 + st_cs * 8, (ushort_t*)Bs + i * 512);
    }
    __syncthreads();
#pragma unroll
    for (int kq = 0; kq < 2; ++kq) {
      bf16x8 af[4], bfr[4];
#pragma unroll
      for (int mi = 0; mi < 4; ++mi)
        af[mi] = *(const bf16x8*)&As[wm + mi*16 + rq][((kq*4 + kg) ^ (rq & 7)) * 8];
#pragma unroll
      for (int ni = 0; ni < 4; ++ni)
        bfr[ni] = *(const bf16x8*)&Bs[wn + ni*16 + rq][((kq*4 + kg) ^ (rq & 7)) * 8];
#pragma unroll
      for (int mi = 0; mi < 4; ++mi)
#pragma unroll
        for (int ni = 0; ni < 4; ++ni)
          acc[mi][ni] = mfma16(af[mi], bfr[ni], acc[mi][ni]);
    }
  }

  float bv4[4];
#pragma unroll
  for (int ni = 0; ni < 4; ++ni) bv4[ni] = bias[col0 + wn + ni*16 + rq];
#pragma unroll
  for (int mi = 0; mi < 4; ++mi)
#pragma unroll
    for (int ni = 0; ni < 4; ++ni)
#pragma unroll
      for (int rr = 0; rr < 4; ++rr) {
        int row = row0 + wm + mi*16 + kg*4 + rr;
        int col = col0 + wn + ni*16 + rq;
        size_t idx = (size_t)row * Nn + col;
        float pre = acc[mi][ni][rr] + bv4[ni];
        Out[idx] = bf2f(Ob[idx]) + (pre > 0.f ? pre : 0.f);
      }
}

// ---------------------------------------------------------------------------
// Flash attention (no-max softmax). BQ=128, BKV=128, d=64, all bf16.
// S^T = K*Q^T. K-tile [128][64] and V^T-tile [64][128] ALIAS one 16 KB LDS
// buffer (K read only in S phase, V only in PV; separated by barriers).
// Ps[128][128] bf16 with 4-bit XOR swizzle. 49 KB -> 3 blocks/CU (LDS-bound).
// ---------------------------------------------------------------------------
__global__ __launch_bounds__(256, 2)
void attn_kernel(const ushort_t* __restrict__ Qp,
                 const ushort_t* __restrict__ Kp,
                 const ushort_t* __restrict__ Vt,
                 ushort_t* __restrict__ Ob)
{
  const float sc2 = 0.045084439f;  // (1/32) * log2(e)
  const int qt = blockIdx.x;       // 0..15
  const int bh = blockIdx.y;       // 0..63
  const int b = bh >> 4, h = bh & 15;
  const int q0 = qt * 128;

  __shared__ __align__(16) ushort_t KVs[8192];     // K[128][64] / V^T[64][128]
  __shared__ __align__(16) ushort_t Ps[128][128];
  __shared__ float reds[2][128];

  const int tid = threadIdx.x, lane = tid & 63, wave = tid >> 6;
  const int whalf = wave >> 1;
  const int wsec  = wave & 1;
  const int rq = lane & 15, kg = lane >> 4;

  const size_t qkbase = (size_t)(b * 2048) * 1024 + h * 64;

  // stage Q tile (128x64) into KVs, 3-bit chunk swizzle
#pragma unroll
  for (int r = 0; r < 4; ++r) {
    int i = wave * 4 + r;
    int row = i * 8 + (lane >> 3);
    int cs = (lane & 7) ^ (lane >> 3);
    gld_lds16(Qp + qkbase + (size_t)(q0 + row) * 1024 + cs * 8, KVs + i * 512);
  }
  __syncthreads();

  // preload Q B-frags scaled by sc2: aq[ni][kq], q = wsec*64+ni*16+rq
  bf16x8 aq[4][2];
#pragma unroll
  for (int ni = 0; ni < 4; ++ni)
#pragma unroll
    for (int kq = 0; kq < 2; ++kq) {
      int row = wsec*64 + ni*16 + rq;
      int ch = (kq*4 + kg) ^ (rq & 7);
      bf16x8 t = *(const bf16x8*)&KVs[row * 64 + ch * 8];
#pragma unroll
      for (int e = 0; e < 8; ++e)
        t[e] = (short)f2bf(bf2f((ushort_t)t[e]) * sc2);
      aq[ni][kq] = t;
    }

  floatx4 oacc[4][2];
  float l_st[4];
#pragma unroll
  for (int mi = 0; mi < 4; ++mi) {
    oacc[mi][0] = (floatx4){0.f,0.f,0.f,0.f};
    oacc[mi][1] = (floatx4){0.f,0.f,0.f,0.f};
  }
#pragma unroll
  for (int ni = 0; ni < 4; ++ni) l_st[ni] = 0.f;

  for (int kt = 0; kt < 16; ++kt) {
    const int kv0 = kt * 128;
    __syncthreads();   // (1) prev PV done reading Ps + KVs(V)
    // stage K (128 kv x 64 d) into KVs
#pragma unroll
    for (int r = 0; r < 4; ++r) {
      int i = wave * 4 + r;
      int row = i * 8 + (lane >> 3);
      int cs = (lane & 7) ^ (lane >> 3);
      gld_lds16(Kp + qkbase + (size_t)(kv0 + row) * 1024 + cs * 8, KVs + i * 512);
    }
    __syncthreads();   // (2) K landed

    // S^T = K * Q^T  (mi = kv tile, ni = q tile)
    floatx4 s[4][4];
#pragma unroll
    for (int mi = 0; mi < 4; ++mi)
#pragma unroll
      for (int ni = 0; ni < 4; ++ni) s[mi][ni] = (floatx4){0.f,0.f,0.f,0.f};
#pragma unroll
    for (int kq = 0; kq < 2; ++kq) {
      bf16x8 ak[4];
#pragma unroll
      for (int mi = 0; mi < 4; ++mi) {
        int row = whalf*64 + mi*16 + rq;
        int ch = (kq*4 + kg) ^ (rq & 7);
        ak[mi] = *(const bf16x8*)&KVs[row * 64 + ch * 8];
      }
#pragma unroll
      for (int mi = 0; mi < 4; ++mi)
#pragma unroll
        for (int ni = 0; ni < 4; ++ni)
          s[mi][ni] = mfma16(ak[mi], aq[ni][kq], s[mi][ni]);
    }
    __syncthreads();   // (3) all waves done reading K from KVs

    // stage V^T (64 dv x 128 kv) into KVs (aliased over K)
#pragma unroll
    for (int r = 0; r < 4; ++r) {
      int i = wave * 4 + r;
      int dv = i * 4 + (lane >> 4);
      int cs = (lane & 15) ^ (dv & 7);
      gld_lds16(Vt + (size_t)(h*64 + dv) * 8192 + b * 2048 + kv0 + cs * 8,
                KVs + i * 512);
    }

    // p = 2^s ; per-lane partial row sums; pack + write Ps
#pragma unroll
    for (int mi = 0; mi < 4; ++mi)
#pragma unroll
      for (int ni = 0; ni < 4; ++ni)
#pragma unroll
        for (int rr = 0; rr < 4; ++rr)
          s[mi][ni][rr] = __builtin_amdgcn_exp2f(s[mi][ni][rr]);
#pragma unroll
    for (int ni = 0; ni < 4; ++ni) {
      float t = 0.f;
#pragma unroll
      for (int mi = 0; mi < 4; ++mi)
        t += (s[mi][ni][0] + s[mi][ni][1]) + (s[mi][ni][2] + s[mi][ni][3]);
      l_st[ni] += t;
    }
#pragma unroll
    for (int mi = 0; mi < 4; ++mi)
#pragma unroll
      for (int ni = 0; ni < 4; ++ni) {
        int q = wsec*64 + ni*16 + rq;
        int chunk = (whalf*8 + mi*2 + (kg >> 1)) ^ rq;   // kv>>3 swizzled by q&15
        int colu = chunk*8 + (kg & 1)*4;
        uint2 w;
        w.x = pk2(s[mi][ni][0], s[mi][ni][1]);
        w.y = pk2(s[mi][ni][2], s[mi][ni][3]);
        *(uint2*)&Ps[q][colu] = w;
      }
    __syncthreads();   // (4) V + Ps landed

    // O += P V : wave = (whalf: 64 q rows) x (wsec: 32 dv cols)
#pragma unroll
    for (int kp = 0; kp < 4; ++kp) {
      bf16x8 pf[4], vf[2];
#pragma unroll
      for (int mi = 0; mi < 4; ++mi) {
        int row = whalf*64 + mi*16 + rq;
        int slot = (kp*4 + kg) ^ rq;    // unswizzle by q&15
        pf[mi] = *(const bf16x8*)&Ps[row][slot * 8];
      }
#pragma unroll
      for (int n2 = 0; n2 < 2; ++n2) {
        int dv = wsec*32 + n2*16 + rq;
        int ch = (kp*4 + kg) ^ (rq & 7);
        vf[n2] = *(const bf16x8*)&KVs[dv * 128 + ch * 8];
      }
#pragma unroll
      for (int mi = 0; mi < 4; ++mi)
#pragma unroll
        for (int n2 = 0; n2 < 2; ++n2)
          oacc[mi][n2] = mfma16(pf[mi], vf[n2], oacc[mi][n2]);
    }
  }

  // combine l: across kg groups, then across kv-half waves via LDS
#pragma unroll
  for (int ni = 0; ni < 4; ++ni) {
    l_st[ni] += __shfl_xor(l_st[ni], 16, 64);
    l_st[ni] += __shfl_xor(l_st[ni], 32, 64);
  }
  if (lane < 16) {
#pragma unroll
    for (int ni = 0; ni < 4; ++ni)
      reds[whalf][wsec*64 + ni*16 + rq] = l_st[ni];
  }
  __syncthreads();

  // epilogue: Oh = Qh + O/l
#pragma unroll
  for (int mi = 0; mi < 4; ++mi)
#pragma unroll
    for (int rr = 0; rr < 4; ++rr) {
      int row = whalf*64 + mi*16 + kg*4 + rr;
      float linv = 1.0f / (reds[0][row] + reds[1][row]);
#pragma unroll
      for (int n2 = 0; n2 < 2; ++n2) {
        int col = wsec*32 + n2*16 + rq;
        size_t idx = qkbase + (size_t)(q0 + row) * 1024 + col;
        float ov = oacc[mi][n2][rr] * linv + bf2f(Qp[idx]);
        Ob[idx] = f2bf(ov);
      }
    }
}

// ---------------------------------------------------------------------------
extern "C" void kernel_launch(void* const* d_in, const int* in_sizes, int n_in,
                              void* d_out, int out_size, void* d_ws, size_t ws_size,
                              hipStream_t stream)
{
  const float* Q  = (const float*)d_in[0];
  const float* K  = (const float*)d_in[1];
  const float* Wq = (const float*)d_in[2];
  const float* bq = (const float*)d_in[3];
  const float* Wk = (const float*)d_in[4];
  const float* bk = (const float*)d_in[5];
  const float* Wv = (const float*)d_in[6];
  const float* bv = (const float*)d_in[7];
  const float* Wo = (const float*)d_in[8];
  const float* bo = (const float*)d_in[9];
  float* Out = (float*)d_out;

  ushort_t* ws = (ushort_t*)d_ws;
  const size_t E = (size_t)8192 * 1024;
  const size_t WSZ = (size_t)1024 * 1024;
  ushort_t* Qb  = ws;            // aliased by Ob after attention
  ushort_t* Kb  = ws + E;
  ushort_t* Qp  = ws + 2*E;
  ushort_t* Kp  = ws + 3*E;
  ushort_t* Vt  = ws + 4*E;      // bf16 V^T [1024][8192]
  ushort_t* Wqb = ws + 5*E;
  ushort_t* Wkb = ws + 5*E + WSZ;
  ushort_t* Wvb = ws + 5*E + 2*WSZ;
  ushort_t* Wob = ws + 5*E + 3*WSZ;
  ushort_t* Ob  = Qb;

  cvt4<<<dim3(4096, 1, 2), 256, 0, stream>>>(Q, K, K, K, Qb, Kb, Kb, Kb, 1048576);
  cvt4<<<dim3(512, 1, 4), 256, 0, stream>>>(Wq, Wk, Wv, Wo, Wqb, Wkb, Wvb, Wob, 131072);

  dim3 blk(256);
  gemm_qkv<<<dim3(8, 64, 3), blk, 0, stream>>>(Qb, Kb, Wqb, Wkb, Wvb,
                                               bq, bk, bv, Qp, Kp, Vt);
  attn_kernel<<<dim3(16, 64), blk, 0, stream>>>(Qp, Kp, Vt, Ob);
  gemm_out<<<dim3(8, 64), blk, 0, stream>>>(Ob, Wob, bo, Out);
}